// Round 8
// baseline (74.290 us; speedup 1.0000x reference)
//
#include <hip/hip_runtime.h>

// LinearCondensed: out[b,o] = sum_k w[o,k] * x[b, idx[o,k]] + bias[o]
// B=2048, IN_F=4096, OUT_F=4096, K=32, f32 in/out (idx int32).
//
// v7: DEEP-ILP gather. Stage-once read-only LDS (f16, 8 rows packed per
// column -> one ds_read_b128 = col c of 8 rows). Each o-chunk issues ALL 32
// ds_read_b128 into vv[32] (128 VGPRs) before consuming -> compiler emits
// incremental lgkmcnt waits, LDS pipe fully pipelined per wave (fixes the
// ~300cy stall-per-8-reads that capped v2-v6 at ~41us with all pipes <25%).
// 256-thread blocks: VGPR ~215 -> 2 waves/SIMD -> 8 waves/CU = 2 co-resident
// blocks (2x64KB LDS), so one block's staging hides under the other's
// gathers. bid = oq*256 + g keeps the 4 blocks sharing a row-group on one
// XCD (x slice 2MB < 4MB L2 -> x read from HBM exactly once).

constexpr int IN_F  = 4096;
constexpr int OUT_F = 4096;
constexpr int K     = 32;
constexpr int BT    = 8;                       // batch rows per block
constexpr int THREADS = 256;
constexpr int OCH   = 4;                       // o-chunks per thread
constexpr int OPB   = OCH * THREADS;           // 1024 outputs per block
constexpr int CPT   = IN_F / THREADS;          // 16 columns staged per thread

typedef __fp16 h2_t __attribute__((ext_vector_type(2)));

__device__ __forceinline__ int pack_f16(float lo, float hi) {
    union { h2_t h; int i; } cv;
    cv.h = __builtin_amdgcn_cvt_pkrtz(lo, hi);   // v_cvt_pkrtz_f16_f32
    return cv.i;
}
__device__ __forceinline__ float h_lo(int u) {
    union { int i; h2_t h; } cv; cv.i = u; return (float)cv.h[0];
}
__device__ __forceinline__ float h_hi(int u) {
    union { int i; h2_t h; } cv; cv.i = u; return (float)cv.h[1];
}

__global__ __launch_bounds__(THREADS, 1)
void lc_kernel(const float* __restrict__ x,
               const float* __restrict__ w,
               const float* __restrict__ bias,
               const int* __restrict__ idx,
               float* __restrict__ out) {
    // xs[c] = {rows 0..7 of col c, 4x packed f16 pairs} -- 64 KiB
    __shared__ int4 xs[IN_F];
    const int tid = threadIdx.x;
    const int oq  = blockIdx.x >> 8;           // 0..3  (output quarter)
    const int g   = blockIdx.x & 255;          // 0..255 (8-row group)
    const int b0  = g * BT;

    // ---- prologue: stage 8 rows as packed f16, one barrier ----
    {
        const float* xr = x + (size_t)b0 * IN_F;
#pragma unroll
        for (int j = 0; j < CPT; ++j) {
            const int c = tid + j * THREADS;
            float v[BT];
#pragma unroll
            for (int r = 0; r < BT; ++r) v[r] = xr[(size_t)r * IN_F + c];
            int4 pk;
            pk.x = pack_f16(v[0], v[1]);
            pk.y = pack_f16(v[2], v[3]);
            pk.z = pack_f16(v[4], v[5]);
            pk.w = pack_f16(v[6], v[7]);
            xs[c] = pk;
        }
    }
    __syncthreads();

    const char* xb = reinterpret_cast<const char*>(&xs[0]);

#pragma unroll 1
    for (int oc = 0; oc < OCH; ++oc) {
        const int o = oq * OPB + oc * THREADS + tid;

        // this o's idx row (as byte offsets) + weight row, registers
        int   ao[K];
        float wr[K];
        const int4*   ip = reinterpret_cast<const int4*>(idx + (size_t)o * K);
        const float4* wp = reinterpret_cast<const float4*>(w + (size_t)o * K);
#pragma unroll
        for (int kk = 0; kk < K / 4; ++kk) {
            int4   i4 = ip[kk];
            float4 w4 = wp[kk];
            ao[4*kk+0] = i4.x << 4;  ao[4*kk+1] = i4.y << 4;
            ao[4*kk+2] = i4.z << 4;  ao[4*kk+3] = i4.w << 4;
            wr[4*kk+0] = w4.x;  wr[4*kk+1] = w4.y;
            wr[4*kk+2] = w4.z;  wr[4*kk+3] = w4.w;
        }
        const float bv = bias[o];

        // ---- issue ALL 32 gathers first (32-deep MLP, 128 VGPRs) ----
        int4 vv[K];
#pragma unroll
        for (int k = 0; k < K; ++k)
            vv[k] = *reinterpret_cast<const int4*>(xb + ao[k]);

        // ---- consume: 256 fma_mix into 8 row-accumulators ----
        float acc[BT];
#pragma unroll
        for (int r = 0; r < BT; ++r) acc[r] = bv;
#pragma unroll
        for (int k = 0; k < K; ++k) {
            const float wk = wr[k];
            acc[0] += wk * h_lo(vv[k].x);  acc[1] += wk * h_hi(vv[k].x);
            acc[2] += wk * h_lo(vv[k].y);  acc[3] += wk * h_hi(vv[k].y);
            acc[4] += wk * h_lo(vv[k].z);  acc[5] += wk * h_hi(vv[k].z);
            acc[6] += wk * h_lo(vv[k].w);  acc[7] += wk * h_hi(vv[k].w);
        }

        // coalesced stores: 8 rows x 1KB per block-row
        float* op = out + (size_t)b0 * OUT_F + o;
#pragma unroll
        for (int r = 0; r < BT; ++r) op[(size_t)r * OUT_F] = acc[r];
    }
}

extern "C" void kernel_launch(void* const* d_in, const int* in_sizes, int n_in,
                              void* d_out, int out_size, void* d_ws, size_t ws_size,
                              hipStream_t stream) {
    const float* x    = (const float*)d_in[0];
    const float* w    = (const float*)d_in[1];
    const float* bias = (const float*)d_in[2];
    const int*   idx  = (const int*)d_in[3];
    float* out = (float*)d_out;

    const int Bv = in_sizes[0] / IN_F;            // 2048
    const int groups = Bv / BT;                   // 256
    const int nblocks = groups * (OUT_F / OPB);   // 1024
    lc_kernel<<<dim3(nblocks), dim3(THREADS), 0, stream>>>(x, w, bias, idx, out);
}

// Round 9
// 67.599 us; speedup vs baseline: 1.0990x; 1.0990x over previous
//
#include <hip/hip_runtime.h>

// LinearCondensed: out[b,o] = sum_k w[o,k] * x[b, idx[o,k]] + bias[o]
// B=2048, IN_F=4096, OUT_F=4096, K=32, f32 in/out (idx int32).
//
// v8: TWO kernels.
//  1) lc_prep: pack x once into xT[g][c] = int4{f16 rows 8g..8g+7 of col c}
//     -- the exact LDS image (deduplicates the f32->f16 pack that v2-v7
//     repeated per block: 64 scalar loads + 32 cvts per thread per tile).
//  2) lc_main: block = 8-row group x 256 outputs. Stage = 16 linear
//     global_load_lds_dwordx4 (64KB memcpy, no VGPR round-trip), ONE barrier,
//     then pure gather: 32 ds_read_b128 + 256 fma_mix per thread. 64KB LDS ->
//     2 blocks/CU; a finishing block's successor stages while the other block
//     gathers (block-level pipelining, no intra-block restage stalls).
//     bid = oc*groups + g -> XCD = g%8: each XCD's 32-group tile set (2MB)
//     stays L2-resident across all 16 oc passes -> xT read from HBM ~once.
// Fallback to the proven v5b kernel if ws_size < 16MB.

constexpr int IN_F  = 4096;
constexpr int OUT_F = 4096;
constexpr int K     = 32;
constexpr int BT    = 8;                        // rows per group
constexpr int MT    = 256;                      // main kernel threads
constexpr long long XT_BYTES = (long long)(2048 / BT) * IN_F * 16;  // 16 MiB

typedef __fp16 h2_t __attribute__((ext_vector_type(2)));

__device__ __forceinline__ int pack_f16(float lo, float hi) {
    union { h2_t h; int i; } cv;
    cv.h = __builtin_amdgcn_cvt_pkrtz(lo, hi);   // v_cvt_pkrtz_f16_f32
    return cv.i;
}
__device__ __forceinline__ float h_lo(int u) {
    union { int i; h2_t h; } cv; cv.i = u; return (float)cv.h[0];
}
__device__ __forceinline__ float h_hi(int u) {
    union { int i; h2_t h; } cv; cv.i = u; return (float)cv.h[1];
}

// ---------------- prep: x (f32, row-major) -> xT (f16, 8-row interleaved) ---
__global__ __launch_bounds__(256)
void lc_prep(const float* __restrict__ x, int4* __restrict__ xT) {
    const int bid  = blockIdx.x;                 // groups*4 blocks
    const int g    = bid >> 2;
    const int part = bid & 3;
    const int q    = part * 256 + threadIdx.x;   // column-quad 0..1023
    const float4* xr = reinterpret_cast<const float4*>(x + (size_t)g * BT * IN_F);
    float4 r[BT];
#pragma unroll
    for (int i = 0; i < BT; ++i) r[i] = xr[(size_t)i * (IN_F / 4) + q];
    int4* op = xT + (size_t)g * IN_F + 4 * q;
#pragma unroll
    for (int m = 0; m < 4; ++m) {               // column c = 4q+m
        int4 pk;
        pk.x = pack_f16(((const float*)&r[0])[m], ((const float*)&r[1])[m]);
        pk.y = pack_f16(((const float*)&r[2])[m], ((const float*)&r[3])[m]);
        pk.z = pack_f16(((const float*)&r[4])[m], ((const float*)&r[5])[m]);
        pk.w = pack_f16(((const float*)&r[6])[m], ((const float*)&r[7])[m]);
        op[m] = pk;
    }
}

// ---------------- main: stage 64KB tile via global_load_lds, then gather ----
__global__ __launch_bounds__(MT)
void lc_main(const int4* __restrict__ xT,
             const float* __restrict__ w,
             const float* __restrict__ bias,
             const int* __restrict__ idx,
             float* __restrict__ out,
             int groups) {
    __shared__ int4 xs[IN_F];                    // 64 KiB, 2 blocks/CU
    const int tid = threadIdx.x;
    const int g   = blockIdx.x % groups;         // XCD = g%8 (groups%8==0)
    const int oc  = blockIdx.x / groups;
    const int o   = oc * MT + tid;

    // idx/w loads issued first -> land during the stage wait
    int   ao[K];
    float wr[K];
    const int4*   ip = reinterpret_cast<const int4*>(idx + (size_t)o * K);
    const float4* wp = reinterpret_cast<const float4*>(w + (size_t)o * K);
    int4   iq[K / 4];
    float4 wq[K / 4];
#pragma unroll
    for (int kk = 0; kk < K / 4; ++kk) { iq[kk] = ip[kk]; wq[kk] = wp[kk]; }
    const float bv = bias[o];

    // stage: 64KB linear copy, 16 x global_load_lds_dwordx4 per thread.
    // dst = wave-uniform base (+lane*16 implicit); src = per-lane address.
    {
        const char* gsrc = reinterpret_cast<const char*>(xT) + (size_t)g * (IN_F * 16);
        char* lbase = reinterpret_cast<char*>(&xs[0]);
        const int wbase = (tid & 192) << 4;      // wave * 1024
        const int lane16 = tid << 4;             // wbase + lane*16
#pragma unroll
        for (int j = 0; j < 16; ++j) {
            __builtin_amdgcn_global_load_lds(
                (const __attribute__((address_space(1))) unsigned int*)(gsrc + j * 4096 + lane16),
                (__attribute__((address_space(3))) unsigned int*)(lbase + j * 4096 + wbase),
                16, 0, 0);
        }
    }
    __syncthreads();                              // vmcnt(0) drain + barrier

#pragma unroll
    for (int kk = 0; kk < K / 4; ++kk) {
        ao[4*kk+0] = iq[kk].x << 4;  ao[4*kk+1] = iq[kk].y << 4;
        ao[4*kk+2] = iq[kk].z << 4;  ao[4*kk+3] = iq[kk].w << 4;
        wr[4*kk+0] = wq[kk].x;  wr[4*kk+1] = wq[kk].y;
        wr[4*kk+2] = wq[kk].z;  wr[4*kk+3] = wq[kk].w;
    }

    // gather: 32 ds_read_b128, each feeds 8 row-accumulators via fma_mix
    const char* xb = reinterpret_cast<const char*>(&xs[0]);
    float acc[BT];
#pragma unroll
    for (int r = 0; r < BT; ++r) acc[r] = bv;
#pragma unroll
    for (int k = 0; k < K; ++k) {
        int4 v = *reinterpret_cast<const int4*>(xb + ao[k]);
        const float wk = wr[k];
        acc[0] += wk * h_lo(v.x);  acc[1] += wk * h_hi(v.x);
        acc[2] += wk * h_lo(v.y);  acc[3] += wk * h_hi(v.y);
        acc[4] += wk * h_lo(v.z);  acc[5] += wk * h_hi(v.z);
        acc[6] += wk * h_lo(v.w);  acc[7] += wk * h_hi(v.w);
    }

    // coalesced stores: 8 rows x 1KB per block-row
    float* op = out + (size_t)(g * BT) * OUT_F + o;
#pragma unroll
    for (int r = 0; r < BT; ++r) op[(size_t)r * OUT_F] = acc[r];
}

// ---------------- fallback: proven v5b kernel (41us) if ws too small -------
constexpr int FB_THREADS = 512;
constexpr int FB_RPB = 32;
constexpr int FB_ITERS = FB_RPB / BT;            // 4
constexpr int FB_CPT = IN_F / FB_THREADS;        // 8

__global__ __launch_bounds__(FB_THREADS)
void lc_fallback(const float* __restrict__ x,
                 const float* __restrict__ w,
                 const float* __restrict__ bias,
                 const int* __restrict__ idx,
                 float* __restrict__ out,
                 int bchunks) {
    __shared__ int4 xs[IN_F];
    const int tid = threadIdx.x;
    const int ochunk = blockIdx.x / bchunks;
    const int bchunk = blockIdx.x % bchunks;
    const int o = ochunk * FB_THREADS + tid;

    int   ao[K];
    float wr[K];
    const int4*   ip = reinterpret_cast<const int4*>(idx + (size_t)o * K);
    const float4* wp = reinterpret_cast<const float4*>(w + (size_t)o * K);
#pragma unroll
    for (int kk = 0; kk < K / 4; ++kk) {
        int4   i4 = ip[kk];
        float4 w4 = wp[kk];
        ao[4*kk+0] = i4.x << 4;  ao[4*kk+1] = i4.y << 4;
        ao[4*kk+2] = i4.z << 4;  ao[4*kk+3] = i4.w << 4;
        wr[4*kk+0] = w4.x;  wr[4*kk+1] = w4.y;
        wr[4*kk+2] = w4.z;  wr[4*kk+3] = w4.w;
    }
    const float bv = bias[o];
    const int b0 = bchunk * FB_RPB;
    float pf[BT * FB_CPT];

    {
        const float* xr = x + (size_t)b0 * IN_F;
#pragma unroll
        for (int j = 0; j < FB_CPT; ++j)
#pragma unroll
            for (int r = 0; r < BT; ++r)
                pf[j * BT + r] = xr[(size_t)r * IN_F + tid + j * FB_THREADS];
#pragma unroll
        for (int j = 0; j < FB_CPT; ++j) {
            int4 pk;
            pk.x = pack_f16(pf[j*BT+0], pf[j*BT+1]);
            pk.y = pack_f16(pf[j*BT+2], pf[j*BT+3]);
            pk.z = pack_f16(pf[j*BT+4], pf[j*BT+5]);
            pk.w = pack_f16(pf[j*BT+6], pf[j*BT+7]);
            xs[tid + j * FB_THREADS] = pk;
        }
    }
    __syncthreads();
    const char* xb = reinterpret_cast<const char*>(&xs[0]);

#pragma unroll
    for (int it = 0; it < FB_ITERS; ++it) {
        if (it + 1 < FB_ITERS) {
            const float* xr = x + (size_t)(b0 + (it + 1) * BT) * IN_F;
#pragma unroll
            for (int j = 0; j < FB_CPT; ++j)
#pragma unroll
                for (int r = 0; r < BT; ++r)
                    pf[j * BT + r] = xr[(size_t)r * IN_F + tid + j * FB_THREADS];
        }
        float acc[BT];
#pragma unroll
        for (int r = 0; r < BT; ++r) acc[r] = bv;
#pragma unroll
        for (int k = 0; k < K; ++k) {
            int4 v = *reinterpret_cast<const int4*>(xb + ao[k]);
            const float wk = wr[k];
            acc[0] += wk * h_lo(v.x);  acc[1] += wk * h_hi(v.x);
            acc[2] += wk * h_lo(v.y);  acc[3] += wk * h_hi(v.y);
            acc[4] += wk * h_lo(v.z);  acc[5] += wk * h_hi(v.z);
            acc[6] += wk * h_lo(v.w);  acc[7] += wk * h_hi(v.w);
        }
        float* op = out + (size_t)(b0 + it * BT) * OUT_F + o;
#pragma unroll
        for (int r = 0; r < BT; ++r) op[(size_t)r * OUT_F] = acc[r];

        if (it + 1 < FB_ITERS) {
            __syncthreads();
#pragma unroll
            for (int j = 0; j < FB_CPT; ++j) {
                int4 pk;
                pk.x = pack_f16(pf[j*BT+0], pf[j*BT+1]);
                pk.y = pack_f16(pf[j*BT+2], pf[j*BT+3]);
                pk.z = pack_f16(pf[j*BT+4], pf[j*BT+5]);
                pk.w = pack_f16(pf[j*BT+6], pf[j*BT+7]);
                xs[tid + j * FB_THREADS] = pk;
            }
            __syncthreads();
        }
    }
}

extern "C" void kernel_launch(void* const* d_in, const int* in_sizes, int n_in,
                              void* d_out, int out_size, void* d_ws, size_t ws_size,
                              hipStream_t stream) {
    const float* x    = (const float*)d_in[0];
    const float* w    = (const float*)d_in[1];
    const float* bias = (const float*)d_in[2];
    const int*   idx  = (const int*)d_in[3];
    float* out = (float*)d_out;

    const int Bv = in_sizes[0] / IN_F;            // 2048
    const int groups = Bv / BT;                   // 256

    const long long xt_bytes = (long long)groups * IN_F * 16;
    if ((long long)ws_size >= xt_bytes) {
        int4* xT = (int4*)d_ws;
        lc_prep<<<dim3(groups * 4), dim3(256), 0, stream>>>(x, xT);
        const int ochunks = OUT_F / MT;           // 16
        lc_main<<<dim3(ochunks * groups), dim3(MT), 0, stream>>>(
            xT, w, bias, idx, out, groups);
    } else {
        const int bchunks = Bv / FB_RPB;          // 64
        lc_fallback<<<dim3((OUT_F / FB_THREADS) * bchunks), dim3(FB_THREADS), 0, stream>>>(
            x, w, bias, idx, out, bchunks);
    }
}

// Round 10
// 57.270 us; speedup vs baseline: 1.2972x; 1.1803x over previous
//
#include <hip/hip_runtime.h>

// LinearCondensed: out[b,o] = sum_k w[o,k] * x[b, idx[o,k]] + bias[o]
// B=2048, IN_F=4096, OUT_F=4096, K=32, f32 in/out (idx int32).
//
// v9: barrier-free gather. Block = 8-row group x 512 outputs; thread owns ONE
// o (idx/w register-resident for the whole block, never reloaded). Stage the
// 8-row f16 tile once (float4 loads + cvt_pkrtz), ONE barrier, then pure
// gather: 32 ds_read_b128 + 256 fma_mix + 8 stores per thread. 64KB LDS +
// launch_bounds(512,4) -> 2 co-resident blocks/CU: incoming block's stage
// overlaps resident block's gathers (no intra-block restage stalls).
//
// LDS layout swizzle: column c -> slot (c&3)*1024 + (c>>2). A thread packing
// columns 4q..4q+3 writes slots {q, 1024+q, 2048+q, 3072+q}: each
// ds_write_b128 has lane-consecutive 16B addresses = conflict-free (the
// naive layout would be a 16-way write conflict). Reads apply the same
// bijection to idx (setup-time VALU), preserving gather randomness.
//
// bid = oc*256 + g -> XCD = g%8: each XCD's x slice (32 groups, 4MB) stays
// L2-resident across all 8 oc passes -> x read from HBM ~once.

constexpr int IN_F  = 4096;
constexpr int OUT_F = 4096;
constexpr int K     = 32;
constexpr int BT    = 8;                       // batch rows per group
constexpr int THREADS = 512;

typedef __fp16 h2_t __attribute__((ext_vector_type(2)));

__device__ __forceinline__ int pack_f16(float lo, float hi) {
    union { h2_t h; int i; } cv;
    cv.h = __builtin_amdgcn_cvt_pkrtz(lo, hi);   // v_cvt_pkrtz_f16_f32
    return cv.i;
}
__device__ __forceinline__ float h_lo(int u) {
    union { int i; h2_t h; } cv; cv.i = u; return (float)cv.h[0];
}
__device__ __forceinline__ float h_hi(int u) {
    union { int i; h2_t h; } cv; cv.i = u; return (float)cv.h[1];
}

__global__ __launch_bounds__(THREADS, 4)
void lc_kernel(const float* __restrict__ x,
               const float* __restrict__ w,
               const float* __restrict__ bias,
               const int* __restrict__ idx,
               float* __restrict__ out,
               int ngroups) {
    // xs[slot] = packed f16 rows 0..7 of column c, slot = (c&3)*1024 + (c>>2)
    __shared__ int4 xs[IN_F];                   // 64 KiB -> 2 blocks/CU
    const int tid = threadIdx.x;
    const int g   = blockIdx.x % ngroups;       // XCD = g%8 (ngroups%8==0)
    const int oc  = blockIdx.x / ngroups;
    const int o   = oc * THREADS + tid;
    const int b0  = g * BT;

    // ---- stage: 16 float4 loads, 32 cvt_pkrtz, 8 conflict-free b128 writes ----
    {
        const float4* xr = reinterpret_cast<const float4*>(x + (size_t)b0 * IN_F);
#pragma unroll
        for (int j = 0; j < 2; ++j) {
            const int q = tid + j * THREADS;    // column-quad: cols 4q..4q+3
            float4 r[BT];
#pragma unroll
            for (int i = 0; i < BT; ++i) r[i] = xr[(size_t)i * (IN_F / 4) + q];
#pragma unroll
            for (int m = 0; m < 4; ++m) {       // col 4q+m -> slot m*1024+q
                int4 pk;
                pk.x = pack_f16(((const float*)&r[0])[m], ((const float*)&r[1])[m]);
                pk.y = pack_f16(((const float*)&r[2])[m], ((const float*)&r[3])[m]);
                pk.z = pack_f16(((const float*)&r[4])[m], ((const float*)&r[5])[m]);
                pk.w = pack_f16(((const float*)&r[6])[m], ((const float*)&r[7])[m]);
                xs[m * 1024 + q] = pk;
            }
        }
    }

    // idx/w/bias loads issued here: in flight across the barrier wait
    const int4*   ip = reinterpret_cast<const int4*>(idx + (size_t)o * K);
    const float4* wp = reinterpret_cast<const float4*>(w + (size_t)o * K);
    int4   iq[K / 4];
    float4 wq[K / 4];
#pragma unroll
    for (int kk = 0; kk < K / 4; ++kk) { iq[kk] = ip[kk]; wq[kk] = wp[kk]; }
    const float bv = bias[o];

    __syncthreads();                            // the ONLY barrier

    // swizzled byte offsets: slot(t) = (t&3)*1024 + (t>>2), byte = slot*16
    int   ao[K];
    float wr[K];
#pragma unroll
    for (int kk = 0; kk < K / 4; ++kk) {
        ao[4*kk+0] = ((((iq[kk].x & 3) << 10) | (iq[kk].x >> 2)) << 4);
        ao[4*kk+1] = ((((iq[kk].y & 3) << 10) | (iq[kk].y >> 2)) << 4);
        ao[4*kk+2] = ((((iq[kk].z & 3) << 10) | (iq[kk].z >> 2)) << 4);
        ao[4*kk+3] = ((((iq[kk].w & 3) << 10) | (iq[kk].w >> 2)) << 4);
        wr[4*kk+0] = wq[kk].x;  wr[4*kk+1] = wq[kk].y;
        wr[4*kk+2] = wq[kk].z;  wr[4*kk+3] = wq[kk].w;
    }

    // ---- gather: 32 ds_read_b128, each feeds 8 row-accumulators (fma_mix) ----
    const char* xb = reinterpret_cast<const char*>(&xs[0]);
    float acc[BT];
#pragma unroll
    for (int r = 0; r < BT; ++r) acc[r] = bv;
#pragma unroll
    for (int k = 0; k < K; ++k) {
        int4 v = *reinterpret_cast<const int4*>(xb + ao[k]);
        const float wk = wr[k];
        acc[0] += wk * h_lo(v.x);  acc[1] += wk * h_hi(v.x);
        acc[2] += wk * h_lo(v.y);  acc[3] += wk * h_hi(v.y);
        acc[4] += wk * h_lo(v.z);  acc[5] += wk * h_hi(v.z);
        acc[6] += wk * h_lo(v.w);  acc[7] += wk * h_hi(v.w);
    }

    // coalesced stores: 8 rows x 2KB per block-row
    float* op = out + (size_t)b0 * OUT_F + o;
#pragma unroll
    for (int r = 0; r < BT; ++r) op[(size_t)r * OUT_F] = acc[r];
}

extern "C" void kernel_launch(void* const* d_in, const int* in_sizes, int n_in,
                              void* d_out, int out_size, void* d_ws, size_t ws_size,
                              hipStream_t stream) {
    const float* x    = (const float*)d_in[0];
    const float* w    = (const float*)d_in[1];
    const float* bias = (const float*)d_in[2];
    const int*   idx  = (const int*)d_in[3];
    float* out = (float*)d_out;

    const int Bv = in_sizes[0] / IN_F;            // 2048
    const int ngroups = Bv / BT;                  // 256
    const int nocs = OUT_F / THREADS;             // 8
    lc_kernel<<<dim3(nocs * ngroups), dim3(THREADS), 0, stream>>>(
        x, w, bias, idx, out, ngroups);
}

// Round 11
// 55.700 us; speedup vs baseline: 1.3338x; 1.0282x over previous
//
#include <hip/hip_runtime.h>

// LinearCondensed: out[b,o] = sum_k w[o,k] * x[b, idx[o,k]] + bias[o]
// B=2048, IN_F=4096, OUT_F=4096, K=32, f32 in/out (idx int32).
//
// v10 = v9 structure with UNCONSTRAINED registers (launch_bounds(512) only).
// v9's launch_bounds(512,4) forced VGPR=52 -> compiler re-fetched idx/w
// after the barrier (FETCH 36->86MB) and serialized. Lesson (3rd time):
// never pass the min-waves arg when a ~110-reg working set is intentional.
//
// Structure: block = 8-row group x 512 outputs; thread owns ONE o with
// idx/w/bias register-resident for the whole block. Stage the 8-row f16
// tile once (float4 loads + cvt_pkrtz, conflict-free swizzled b128 writes),
// ONE barrier, then pure gather: 32 ds_read_b128 + 256 fma_mix + 8 stores.
// 64KB LDS -> 2 blocks/CU; incoming block's stage overlaps resident block's
// gathers. bid = oc*256 + g -> XCD = g%8: per-XCD x slice (4MB) L2-resident
// across all 8 oc passes.
//
// LDS swizzle: column c -> slot (c&3)*1024 + (c>>2); a thread packing cols
// 4q..4q+3 writes slots {q, 1024+q, 2048+q, 3072+q} = lane-consecutive 16B
// = conflict-free writes. Reads apply the same bijection to idx.

constexpr int IN_F  = 4096;
constexpr int OUT_F = 4096;
constexpr int K     = 32;
constexpr int BT    = 8;                       // batch rows per group
constexpr int THREADS = 512;

typedef __fp16 h2_t __attribute__((ext_vector_type(2)));

__device__ __forceinline__ int pack_f16(float lo, float hi) {
    union { h2_t h; int i; } cv;
    cv.h = __builtin_amdgcn_cvt_pkrtz(lo, hi);   // v_cvt_pkrtz_f16_f32
    return cv.i;
}
__device__ __forceinline__ float h_lo(int u) {
    union { int i; h2_t h; } cv; cv.i = u; return (float)cv.h[0];
}
__device__ __forceinline__ float h_hi(int u) {
    union { int i; h2_t h; } cv; cv.i = u; return (float)cv.h[1];
}

__global__ __launch_bounds__(THREADS)
void lc_kernel(const float* __restrict__ x,
               const float* __restrict__ w,
               const float* __restrict__ bias,
               const int* __restrict__ idx,
               float* __restrict__ out,
               int ngroups) {
    // xs[slot] = packed f16 rows 0..7 of column c, slot = (c&3)*1024 + (c>>2)
    __shared__ int4 xs[IN_F];                   // 64 KiB -> 2 blocks/CU
    const int tid = threadIdx.x;
    const int g   = blockIdx.x % ngroups;       // XCD = g%8 (ngroups%8==0)
    const int oc  = blockIdx.x / ngroups;
    const int o   = oc * THREADS + tid;
    const int b0  = g * BT;

    // idx/w/bias loads issued FIRST so they overlap the staging loads.
    const int4*   ip = reinterpret_cast<const int4*>(idx + (size_t)o * K);
    const float4* wp = reinterpret_cast<const float4*>(w + (size_t)o * K);
    int4   iq[K / 4];
    float4 wq[K / 4];
#pragma unroll
    for (int kk = 0; kk < K / 4; ++kk) { iq[kk] = ip[kk]; wq[kk] = wp[kk]; }
    const float bv = bias[o];

    // ---- stage: 16 float4 loads, 64 cvt_pkrtz, 8 conflict-free b128 writes ----
    {
        const float4* xr = reinterpret_cast<const float4*>(x + (size_t)b0 * IN_F);
#pragma unroll
        for (int j = 0; j < 2; ++j) {
            const int q = tid + j * THREADS;    // column-quad: cols 4q..4q+3
            float4 r[BT];
#pragma unroll
            for (int i = 0; i < BT; ++i) r[i] = xr[(size_t)i * (IN_F / 4) + q];
#pragma unroll
            for (int m = 0; m < 4; ++m) {       // col 4q+m -> slot m*1024+q
                int4 pk;
                pk.x = pack_f16(((const float*)&r[0])[m], ((const float*)&r[1])[m]);
                pk.y = pack_f16(((const float*)&r[2])[m], ((const float*)&r[3])[m]);
                pk.z = pack_f16(((const float*)&r[4])[m], ((const float*)&r[5])[m]);
                pk.w = pack_f16(((const float*)&r[6])[m], ((const float*)&r[7])[m]);
                xs[m * 1024 + q] = pk;
            }
        }
    }

    // swizzled byte offsets computed PRE-barrier so iq dies early:
    // slot(t) = (t&3)*1024 + (t>>2), byte = slot*16
    int   ao[K];
    float wr[K];
#pragma unroll
    for (int kk = 0; kk < K / 4; ++kk) {
        ao[4*kk+0] = ((((iq[kk].x & 3) << 10) | (iq[kk].x >> 2)) << 4);
        ao[4*kk+1] = ((((iq[kk].y & 3) << 10) | (iq[kk].y >> 2)) << 4);
        ao[4*kk+2] = ((((iq[kk].z & 3) << 10) | (iq[kk].z >> 2)) << 4);
        ao[4*kk+3] = ((((iq[kk].w & 3) << 10) | (iq[kk].w >> 2)) << 4);
        wr[4*kk+0] = wq[kk].x;  wr[4*kk+1] = wq[kk].y;
        wr[4*kk+2] = wq[kk].z;  wr[4*kk+3] = wq[kk].w;
    }

    __syncthreads();                            // the ONLY barrier

    // ---- gather: 32 ds_read_b128, each feeds 8 row-accumulators (fma_mix) ----
    const char* xb = reinterpret_cast<const char*>(&xs[0]);
    float acc[BT];
#pragma unroll
    for (int r = 0; r < BT; ++r) acc[r] = bv;
#pragma unroll
    for (int k = 0; k < K; ++k) {
        int4 v = *reinterpret_cast<const int4*>(xb + ao[k]);
        const float wk = wr[k];
        acc[0] += wk * h_lo(v.x);  acc[1] += wk * h_hi(v.x);
        acc[2] += wk * h_lo(v.y);  acc[3] += wk * h_hi(v.y);
        acc[4] += wk * h_lo(v.z);  acc[5] += wk * h_hi(v.z);
        acc[6] += wk * h_lo(v.w);  acc[7] += wk * h_hi(v.w);
    }

    // coalesced stores: 8 rows x 2KB per block-row
    float* op = out + (size_t)b0 * OUT_F + o;
#pragma unroll
    for (int r = 0; r < BT; ++r) op[(size_t)r * OUT_F] = acc[r];
}

extern "C" void kernel_launch(void* const* d_in, const int* in_sizes, int n_in,
                              void* d_out, int out_size, void* d_ws, size_t ws_size,
                              hipStream_t stream) {
    const float* x    = (const float*)d_in[0];
    const float* w    = (const float*)d_in[1];
    const float* bias = (const float*)d_in[2];
    const int*   idx  = (const int*)d_in[3];
    float* out = (float*)d_out;

    const int Bv = in_sizes[0] / IN_F;            // 2048
    const int ngroups = Bv / BT;                  // 256
    const int nocs = OUT_F / THREADS;             // 8
    lc_kernel<<<dim3(nocs * ngroups), dim3(THREADS), 0, stream>>>(
        x, w, bias, idx, out, ngroups);
}